// Round 7
// baseline (677.021 us; speedup 1.0000x reference)
//
#include <hip/hip_runtime.h>
#include <cstdint>
#include <cstddef>

typedef __bf16 bf16_t;
typedef __bf16 bf16x8 __attribute__((ext_vector_type(8)));
typedef float  f32x4  __attribute__((ext_vector_type(4)));

#define SEQ 2048
#define NH  16
#define HD  128
#define MM  4096   // b*s rows
#define KK  2048

// async global->LDS, 16B per lane, LDS dest = wave-uniform base + lane*16
#define ASYNC16(g, l) __builtin_amdgcn_global_load_lds( \
    (const __attribute__((address_space(1))) void*)(g), \
    (__attribute__((address_space(3))) void*)(l), 16, 0, 0)

// ---------------------------------------------------------------- one cast kernel
__global__ __launch_bounds__(256) void cast_all(const float* __restrict__ x,
                                                const float* __restrict__ Wq,
                                                const float* __restrict__ Wk,
                                                const float* __restrict__ Wv,
                                                const float* __restrict__ Wo,
                                                bf16_t* __restrict__ xb,
                                                bf16_t* __restrict__ wqkv,
                                                bf16_t* __restrict__ wob) {
    int i = blockIdx.x * 256 + threadIdx.x;     // 0..6M-1 float4 groups
    const float* src;
    bf16_t* dst;
    int off;
    if (i < 2097152) { src = x; dst = xb; off = i; }
    else {
        int j = i - 2097152;
        int sel = j >> 20; off = j & 0xFFFFF;
        if (sel < 3) { src = (sel == 0) ? Wq : (sel == 1) ? Wk : Wv; dst = wqkv + (size_t)sel * 4194304; }
        else         { src = Wo; dst = wob; }
    }
    float4 v = ((const float4*)src)[off];
    union { bf16_t h[4]; uint2 u; } t;
    t.h[0] = (bf16_t)v.x; t.h[1] = (bf16_t)v.y;
    t.h[2] = (bf16_t)v.z; t.h[3] = (bf16_t)v.w;
    ((uint2*)dst)[off] = t.u;
}

// ---------------------------------------------------------------- GEMM: 1 wave = 64x64 tile,
// fragments loaded global->VGPR directly (no LDS, no barriers). Register-rotated
// prefetch; compiler inserts fine-grained vmcnt(N) on register deps (never vmcnt(0)).
// A: [M,KK] bf16 rm; B: [N,KK] bf16 rm. MODE 1: fp32 out [M,2048]. MODE 3: QKV+rope.
#define MFMA16(a, b, c) __builtin_amdgcn_mfma_f32_16x16x32_bf16(a, b, c, 0, 0, 0)

template<int MODE>
__device__ __forceinline__ void gemm_body(bf16_t* __restrict__ epi,
                                          const bf16_t* __restrict__ A,
                                          const bf16_t* __restrict__ B,
                                          void* __restrict__ Cout,
                                          bf16_t* __restrict__ Kout,
                                          bf16_t* __restrict__ Vout,
                                          const int* __restrict__ pos) {
    const int l = threadIdx.x;                  // 0..63 (1 wave per block)
    const int lane16 = l & 15, quad = l >> 4;
    const int tm = blockIdx.y, tn = blockIdx.x;

    const bf16_t* pa[4];
    const bf16_t* pb[4];
    for (int i = 0; i < 4; i++) {
        pa[i] = A + (size_t)(tm * 64 + i * 16 + lane16) * KK + quad * 8;
        pb[i] = B + (size_t)(tn * 64 + i * 16 + lane16) * KK + quad * 8;
    }

    f32x4 acc[4][4];
    for (int i = 0; i < 4; i++)
        for (int j = 0; j < 4; j++) acc[i][j] = (f32x4){0.f, 0.f, 0.f, 0.f};

    bf16x8 a[4], b[4];
    for (int i = 0; i < 4; i++) a[i] = *(const bf16x8*)pa[i];
    for (int i = 0; i < 4; i++) b[i] = *(const bf16x8*)pb[i];

    for (int k0 = 32; k0 < KK; k0 += 32) {
        bf16x8 an[4], bn[4];
        for (int i = 0; i < 4; i++) an[i] = *(const bf16x8*)(pa[i] + k0);   // prefetch k
        for (int i = 0; i < 4; i++) bn[i] = *(const bf16x8*)(pb[i] + k0);
        for (int i = 0; i < 4; i++)
            for (int j = 0; j < 4; j++)
                acc[i][j] = MFMA16(a[i], b[j], acc[i][j]);                 // compute k-1
        for (int i = 0; i < 4; i++) { a[i] = an[i]; b[i] = bn[i]; }
    }
    for (int i = 0; i < 4; i++)
        for (int j = 0; j < 4; j++)
            acc[i][j] = MFMA16(a[i], b[j], acc[i][j]);

    if (MODE == 1) {
        // fp32 row-major: 16 lanes x 4B = full 64B lines
        const int mbase = tm * 64;
        const int nbase = tn * 64;
        for (int i = 0; i < 4; i++)
            for (int j = 0; j < 4; j++) {
                const int n  = nbase + j * 16 + lane16;
                const int m0 = mbase + i * 16 + quad * 4;
                for (int r = 0; r < 4; r++)
                    ((float*)Cout)[(size_t)(m0 + r) * 2048 + n] = acc[i][j][r];
            }
        return;
    }

    // ---------------- MODE 3: QKV epilogue, wave-private LDS transpose ----------------
    const int n0   = tn * 64;
    const int sel  = n0 >> 11;                  // 0=Q 1=K 2=V
    const int hh   = (n0 & 2047) >> 7;          // head
    const int d0   = n0 & 127;                  // 0 or 64 (half-head)
    const int m0g  = tm * 64;
    const int bidx = m0g >> 11;
    const int s0   = m0g & 2047;
    const int rl = l >> 3, c = (l & 7) * 8;     // readback: 8 rows/pass, 8 cols/lane

    if (sel < 2) {
        // epi[s_local][d_local] (stride 68), rope fused on readback
        for (int i = 0; i < 4; i++)
            for (int j = 0; j < 4; j++)
                for (int r = 0; r < 4; r++)
                    epi[(i * 16 + quad * 4 + r) * 68 + j * 16 + lane16] = (bf16_t)acc[i][j][r];
        const float qs = (sel == 0) ? 0.08838834764831845f : 1.0f;   // 1/sqrt(128) on Q
        bf16_t* dst = ((sel == 0) ? (bf16_t*)Cout : Kout) + (size_t)(bidx * NH + hh) * SEQ * HD;
        for (int p = 0; p < 8; p++) {
            const int row = p * 8 + rl;
            const int s = s0 + row;
            bf16x8 v = *(const bf16x8*)&epi[row * 68 + c];
            const float pp = (float)pos[bidx * SEQ + s];
            union { bf16_t h8[8]; uint4 u; } o;
            for (int t = 0; t < 4; t++) {
                const int fi = ((d0 + c) >> 1) + t;                  // pair index 0..63
                const float freq = exp2f(-(float)fi * 0.20762050593045857f);
                const float ang = pp * freq;
                const float sn = __sinf(ang), cs = __cosf(ang);
                const float x1 = (float)v[2 * t], x2 = (float)v[2 * t + 1];
                o.h8[2 * t]     = (bf16_t)((x1 * cs - x2 * sn) * qs);
                o.h8[2 * t + 1] = (bf16_t)((x1 * sn + x2 * cs) * qs);
            }
            *(uint4*)(dst + (size_t)s * HD + d0 + c) = o.u;
        }
    } else {
        // V^T: epi[d_local][s_local] (stride 68)
        for (int i = 0; i < 4; i++)
            for (int j = 0; j < 4; j++) {
                union { bf16_t h4[4]; uint2 u; } pk;
                for (int r = 0; r < 4; r++) pk.h4[r] = (bf16_t)acc[i][j][r];
                *(uint2*)&epi[(j * 16 + lane16) * 68 + i * 16 + quad * 4] = pk.u;
            }
        bf16_t* dst = Vout + (size_t)(bidx * NH + hh) * HD * SEQ;
        for (int p = 0; p < 8; p++) {
            const int drow = p * 8 + rl;
            bf16x8 v = *(const bf16x8*)&epi[drow * 68 + c];
            *(uint4*)(dst + (size_t)(d0 + drow) * SEQ + s0 + c) = *(const uint4*)&v;
        }
    }
}

__global__ __launch_bounds__(64, 3) void gemm_qkv(const bf16_t* __restrict__ A,
                                                  const bf16_t* __restrict__ B,
                                                  bf16_t* __restrict__ Qout,
                                                  bf16_t* __restrict__ Kout,
                                                  bf16_t* __restrict__ Vout,
                                                  const int* __restrict__ pos) {
    __shared__ bf16_t epi[64 * 68];
    gemm_body<3>(epi, A, B, (void*)Qout, Kout, Vout, pos);
}

__global__ __launch_bounds__(64, 3) void gemm_out(const bf16_t* __restrict__ A,
                                                  const bf16_t* __restrict__ B,
                                                  float* __restrict__ Cout) {
    gemm_body<1>(nullptr, A, B, (void*)Cout, nullptr, nullptr, nullptr);
}

// ---------------------------------------------------------------- causal flash attention
// Q,K: [b,h,s,d] bf16 (rope applied, Q pre-scaled).  Vt: [b,h,d,s] bf16.  ctx: [b,s,h*d] bf16.
__global__ __launch_bounds__(256) void attn_kernel(const bf16_t* __restrict__ Q,
                                                   const bf16_t* __restrict__ K,
                                                   const bf16_t* __restrict__ Vt,
                                                   bf16_t* __restrict__ ctx) {
    const int flat = blockIdx.x;
    const int bh = flat & 31;
    const int bt = flat >> 5;                   // 0..15
    const int h = bh & 15, b = bh >> 4;
    const bf16_t* Qh = Q  + (size_t)bh * SEQ * HD;
    const bf16_t* Kh = K  + (size_t)bh * SEQ * HD;
    const bf16_t* Vh = Vt + (size_t)bh * HD * SEQ;

    const int tid = threadIdx.x;
    const int w = tid >> 6, l = tid & 63;
    const int lane16 = l & 15, quad = l >> 4;

    __shared__ bf16_t kt[2][16 * 512];
    __shared__ bf16_t vt[2][16 * 512];
    __shared__ bf16_t pbuf[4][1024];

    for (int half = 0; half < 2; half++) {
        const int qt = half ? (31 - bt) : bt;   // q-tile of 64 rows
        const int q0 = qt * 64 + w * 16;

        bf16x8 qf[4];
        {
            const bf16_t* qrow = Qh + (size_t)(q0 + lane16) * HD + quad * 8;
            for (int kc = 0; kc < 4; kc++) qf[kc] = *(const bf16x8*)(qrow + kc * 32);
        }

        f32x4 o[8];
        for (int dt = 0; dt < 8; dt++) o[dt] = (f32x4){0.f, 0.f, 0.f, 0.f};
        float m_s = -INFINITY, l_s = 0.f;       // per-lane: row q = q0 + lane16

        __syncthreads();
        for (int ii = 0; ii < 4; ii++) {
            const int f = w * 4 + ii;
            const int nt = f >> 2, kc = f & 3;
            ASYNC16(Kh + (size_t)(nt * 16 + lane16) * HD + kc * 32 + quad * 8, &kt[0][f * 512]);
            const int dt = f >> 1, kk = f & 1;
            ASYNC16(Vh + (size_t)(dt * 16 + lane16) * SEQ + kk * 32 + quad * 8, &vt[0][f * 512]);
        }

        int cur = 0;
        for (int kb = 0; kb <= qt; kb++) {
            const int k0 = kb * 64;
            __syncthreads();
            if (kb < qt) {
                const int kn = k0 + 64;
                for (int ii = 0; ii < 4; ii++) {
                    const int f = w * 4 + ii;
                    const int nt = f >> 2, kc = f & 3;
                    ASYNC16(Kh + (size_t)(kn + nt * 16 + lane16) * HD + kc * 32 + quad * 8,
                            &kt[1 - cur][f * 512]);
                    const int dt = f >> 1, kk = f & 1;
                    ASYNC16(Vh + (size_t)(dt * 16 + lane16) * SEQ + kn + kk * 32 + quad * 8,
                            &vt[1 - cur][f * 512]);
                }
            }
            const bf16_t* ktc = kt[cur];
            const bf16_t* vtc = vt[cur];

            f32x4 sacc[4];
            for (int nt = 0; nt < 4; nt++) sacc[nt] = (f32x4){0.f, 0.f, 0.f, 0.f};
            for (int nt = 0; nt < 4; nt++)
                for (int kc = 0; kc < 4; kc++) {
                    bf16x8 kf = *(const bf16x8*)&ktc[(nt * 4 + kc) * 512 + l * 8];
                    sacc[nt] = __builtin_amdgcn_mfma_f32_16x16x32_bf16(kf, qf[kc], sacc[nt], 0, 0, 0);
                }
            if (kb == qt) {
                const int qg = q0 + lane16;
                for (int nt = 0; nt < 4; nt++)
                    for (int r = 0; r < 4; r++) {
                        const int kg = k0 + nt * 16 + quad * 4 + r;
                        if (kg > qg) sacc[nt][r] = -INFINITY;
                    }
            }
            float rowmax = sacc[0][0];
            for (int nt = 0; nt < 4; nt++)
                for (int r = 0; r < 4; r++) rowmax = fmaxf(rowmax, sacc[nt][r]);
            rowmax = fmaxf(rowmax, __shfl_xor(rowmax, 16, 64));
            rowmax = fmaxf(rowmax, __shfl_xor(rowmax, 32, 64));
            const float mnew = fmaxf(m_s, rowmax);
            const float a = __expf(m_s - mnew);
            m_s = mnew;
            float ssum = 0.f;
            for (int nt = 0; nt < 4; nt++) {
                union { bf16_t h4[4]; uint2 u; } pk;
                for (int r = 0; r < 4; r++) {
                    const float e = __expf(sacc[nt][r] - mnew);
                    ssum += e;
                    pk.h4[r] = (bf16_t)e;
                }
                const int addr = (nt >> 1) * 512 +
                                 (((nt & 1) * 2 + (quad >> 1)) * 16 + lane16) * 8 +
                                 (quad & 1) * 4;
                *(uint2*)&pbuf[w][addr] = pk.u;
            }
            ssum += __shfl_xor(ssum, 16, 64);
            ssum += __shfl_xor(ssum, 32, 64);
            l_s = l_s * a + ssum;

            float ar[4];
            for (int r = 0; r < 4; r++) ar[r] = __shfl(a, (quad << 2) | r, 16);
            for (int dt = 0; dt < 8; dt++)
                for (int r = 0; r < 4; r++) o[dt][r] *= ar[r];
            for (int kk = 0; kk < 2; kk++) {
                bf16x8 pf = *(const bf16x8*)&pbuf[w][kk * 512 + l * 8];
                for (int dt = 0; dt < 8; dt++) {
                    bf16x8 vf = *(const bf16x8*)&vtc[(dt * 2 + kk) * 512 + l * 8];
                    o[dt] = __builtin_amdgcn_mfma_f32_16x16x32_bf16(pf, vf, o[dt], 0, 0, 0);
                }
            }
            cur ^= 1;
        }

        float inv[4];
        for (int r = 0; r < 4; r++) inv[r] = 1.0f / __shfl(l_s, (quad << 2) | r, 16);
        for (int r = 0; r < 4; r++) {
            const int qg = q0 + quad * 4 + r;
            bf16_t* dst = ctx + ((size_t)(b * SEQ + qg)) * (NH * HD) + h * HD;
            for (int dt = 0; dt < 8; dt++)
                dst[dt * 16 + lane16] = (bf16_t)(o[dt][r] * inv[r]);
        }
        __syncthreads();
    }
}

// ---------------------------------------------------------------- launch
extern "C" void kernel_launch(void* const* d_in, const int* in_sizes, int n_in,
                              void* d_out, int out_size, void* d_ws, size_t ws_size,
                              hipStream_t stream) {
    const float* x  = (const float*)d_in[0];
    const int* pos  = (const int*)d_in[1];
    const float* Wq = (const float*)d_in[2];
    const float* Wk = (const float*)d_in[3];
    const float* Wv = (const float*)d_in[4];
    const float* Wo = (const float*)d_in[5];

    char* ws = (char*)d_ws;
    bf16_t* xb   = (bf16_t*)(ws);
    bf16_t* wqkv = (bf16_t*)(ws + (16u << 20));   // [6144,2048]
    bf16_t* wob  = (bf16_t*)(ws + (40u << 20));
    bf16_t* Qb   = (bf16_t*)(ws + (48u << 20));
    bf16_t* Kb   = (bf16_t*)(ws + (64u << 20));
    bf16_t* Vt   = (bf16_t*)(ws + (80u << 20));
    bf16_t* ctx  = (bf16_t*)(ws + (96u << 20));

    cast_all<<<24576, 256, 0, stream>>>(x, Wq, Wk, Wv, Wo, xb, wqkv, wob);

    dim3 gq(6144 / 64, MM / 64);
    gemm_qkv<<<gq, 64, 0, stream>>>(xb, wqkv, Qb, Kb, Vt, pos);

    attn_kernel<<<512, 256, 0, stream>>>(Qb, Kb, Vt, ctx);

    dim3 gg(2048 / 64, MM / 64);
    gemm_out<<<gg, 64, 0, stream>>>(ctx, wob, (float*)d_out);
}